// Round 8
// baseline (855.112 us; speedup 1.0000x reference)
//
#include <hip/hip_runtime.h>
#include <math.h>

#define HID 64
#define KIN 512

typedef __attribute__((ext_vector_type(8))) short short8;   // 8 bf16 (4 VGPR)
typedef __attribute__((ext_vector_type(4))) float floatx4;  // MFMA acc

// RNE fp32 -> bf16
__device__ inline unsigned bf16pair(float a, float b) {
  unsigned ua = __float_as_uint(a);
  unsigned ub = __float_as_uint(b);
  ua = (ua + 0x7FFFu + ((ua >> 16) & 1u)) >> 16;
  ub = (ub + 0x7FFFu + ((ub >> 16) & 1u)) >> 16;
  return ua | (ub << 16);
}
__device__ inline unsigned short bf16one(float a) {
  unsigned ua = __float_as_uint(a);
  return (unsigned short)((ua + 0x7FFFu + ((ua >> 16) & 1u)) >> 16);
}
__device__ inline float bflo(unsigned u) { return __uint_as_float(u << 16); }
__device__ inline float bfhi(unsigned u) {
  return __uint_as_float(u & 0xffff0000u);
}

// ---- one-time weight prep: transpose + bf16 ----
__global__ __launch_bounds__(256) void prep_kernel(
    const float* __restrict__ We, const float* __restrict__ Wl,
    const float* __restrict__ Wr, unsigned short* __restrict__ wte,
    unsigned short* __restrict__ wlrt) {
  const int blk = blockIdx.x;
  const int tid = threadIdx.x;
  if (blk < 128) {
    const int t = blk * 256 + tid;
    const int c = t >> 9, k = t & 511;
    wte[c * KIN + k] = bf16one(We[k * HID + c]);
  } else {
    const int t = (blk - 128) * 256 + tid;  // 0..24575
    const int mat = t >> 12;                // 0..5
    const int e = t & 4095;
    const int c = e >> 6, k = e & 63;
    const float* src =
        (mat < 3) ? (Wl + (size_t)mat * 4096) : (Wr + (size_t)(mat - 3) * 4096);
    wlrt[(size_t)mat * 4096 + c * 64 + k] = bf16one(src[k * 64 + c]);
  }
}

// ---- encoder: hb = bf16(x @ W_enc + b_enc) via MFMA ----
__global__ __launch_bounds__(256) void enc_kernel(
    const float* __restrict__ x, const unsigned short* __restrict__ wt,
    const float* __restrict__ b, unsigned short* __restrict__ hb, int N) {
  __shared__ uint4 sx[2][256];
  __shared__ uint4 sw[2][256];
  const int t = threadIdx.x;
  const int lane = t & 63;
  const int wid = t >> 6;
  const int m15 = lane & 15;
  const int quad = lane >> 4;
  const int blockBase = blockIdx.x * 64;

  const int rs = t >> 2;
  const int qs = t & 3;
  const int us = rs * 4 + (qs ^ ((rs >> 1) & 3));
  const int gn = blockBase + rs;
  const bool valid = gn < N;
  const float* xp = x + (size_t)(valid ? gn : 0) * KIN + qs * 8;
  const unsigned short* wp = wt + (size_t)rs * KIN + qs * 8;

  const int arow = wid * 16 + m15;
  const int ua = arow * 4 + (quad ^ ((arow >> 1) & 3));
  int ub[4];
#pragma unroll
  for (int c4 = 0; c4 < 4; c4++) {
    const int col = c4 * 16 + m15;
    ub[c4] = col * 4 + (quad ^ ((col >> 1) & 3));
  }

  floatx4 acc[4];
#pragma unroll
  for (int c4 = 0; c4 < 4; c4++)
#pragma unroll
    for (int j = 0; j < 4; j++) acc[c4][j] = 0.f;

  float4 fx0, fx1;
  uint4 wv;
  if (valid) {
    fx0 = *(const float4*)(xp);
    fx1 = *(const float4*)(xp + 4);
  } else {
    fx0 = fx1 = make_float4(0.f, 0.f, 0.f, 0.f);
  }
  wv = *(const uint4*)(wp);

  for (int kc = 0; kc < 16; kc++) {
    const int cur = kc & 1;
    uint4 xu;
    xu.x = bf16pair(fx0.x, fx0.y);
    xu.y = bf16pair(fx0.z, fx0.w);
    xu.z = bf16pair(fx1.x, fx1.y);
    xu.w = bf16pair(fx1.z, fx1.w);
    sx[cur][us] = xu;
    sw[cur][us] = wv;
    __syncthreads();
    if (kc < 15) {
      const int ko = (kc + 1) * 32;
      if (valid) {
        fx0 = *(const float4*)(xp + ko);
        fx1 = *(const float4*)(xp + ko + 4);
      }
      wv = *(const uint4*)(wp + ko);
    }
    const short8 a = __builtin_bit_cast(short8, sx[cur][ua]);
#pragma unroll
    for (int c4 = 0; c4 < 4; c4++) {
      const short8 bf = __builtin_bit_cast(short8, sw[cur][ub[c4]]);
      acc[c4] =
          __builtin_amdgcn_mfma_f32_16x16x32_bf16(a, bf, acc[c4], 0, 0, 0);
    }
  }

#pragma unroll
  for (int c4 = 0; c4 < 4; c4++) {
    const float bias = b[c4 * 16 + m15];
#pragma unroll
    for (int r = 0; r < 4; r++) {
      const int row = blockBase + wid * 16 + quad * 4 + r;
      if (row < N)
        hb[(size_t)row * HID + c4 * 16 + m15] = bf16one(acc[c4][r] + bias);
    }
  }
}

// ---------------- degree histogram ----------------
__global__ void hist_kernel(const int* __restrict__ dst, int* __restrict__ cnt,
                            int E, int N) {
  int e = blockIdx.x * blockDim.x + threadIdx.x;
  if (e < E) {
    int d = dst[e];
    if ((unsigned)d < (unsigned)N) atomicAdd(&cnt[d], 1);
  }
}

// ---------------- parallel scan ----------------
__global__ __launch_bounds__(1024) void scanA_kernel(
    const int* __restrict__ cnt, int* __restrict__ block_sums, int N) {
  __shared__ int red[1024];
  const int tid = threadIdx.x;
  const int i = blockIdx.x * 1024 + tid;
  red[tid] = (i < N) ? cnt[i] : 0;
  __syncthreads();
  for (int off = 512; off > 0; off >>= 1) {
    if (tid < off) red[tid] += red[tid + off];
    __syncthreads();
  }
  if (tid == 0) block_sums[blockIdx.x] = red[0];
}

__global__ __launch_bounds__(128) void scanB_kernel(
    int* __restrict__ block_sums, int* __restrict__ row_start, int nblk,
    int N) {
  __shared__ int part[128];
  const int tid = threadIdx.x;
  part[tid] = (tid < nblk) ? block_sums[tid] : 0;
  __syncthreads();
  for (int off = 1; off < 128; off <<= 1) {
    int t = (tid >= off) ? part[tid - off] : 0;
    __syncthreads();
    part[tid] += t;
    __syncthreads();
  }
  if (tid < nblk) block_sums[tid] = (tid > 0) ? part[tid - 1] : 0;
  if (tid == 127) row_start[N] = part[127];
}

// phase C: local scan + row_start/inv_deg + degree-bin histogram
__global__ __launch_bounds__(1024) void scanC_kernel(
    const int* __restrict__ cnt, const int* __restrict__ block_sums,
    int* __restrict__ row_start, float* __restrict__ inv_deg,
    int* __restrict__ dbin, int N) {
  __shared__ int part[1024];
  const int tid = threadIdx.x;
  const int i = blockIdx.x * 1024 + tid;
  const int v = (i < N) ? cnt[i] : 0;
  part[tid] = v;
  __syncthreads();
  for (int off = 1; off < 1024; off <<= 1) {
    int t = (tid >= off) ? part[tid - off] : 0;
    __syncthreads();
    part[tid] += t;
    __syncthreads();
  }
  if (i < N) {
    row_start[i] = block_sums[blockIdx.x] + part[tid] - v;
    inv_deg[i] = (v > 0) ? 1.0f / (float)v : 0.0f;
    atomicAdd(&dbin[v > 255 ? 255 : v], 1);
  }
}

// scan 256 degree bins -> exclusive dstart
__global__ __launch_bounds__(256) void dscan_kernel(
    const int* __restrict__ dbin, int* __restrict__ dstart) {
  __shared__ int part[256];
  const int tid = threadIdx.x;
  part[tid] = dbin[tid];
  __syncthreads();
  for (int off = 1; off < 256; off <<= 1) {
    int t = (tid >= off) ? part[tid - off] : 0;
    __syncthreads();
    part[tid] += t;
    __syncthreads();
  }
  dstart[tid] = part[tid] - dbin[tid];  // exclusive
}

// scatter node ids into degree-sorted perm (block-aggregated ranks)
__global__ __launch_bounds__(1024) void dscatter_kernel(
    const int* __restrict__ cnt, const int* __restrict__ dstart,
    int* __restrict__ dcur, int* __restrict__ perm, int N) {
  __shared__ int lbin[256];
  __shared__ int lbase[256];
  const int tid = threadIdx.x;
  const int i = blockIdx.x * 1024 + tid;
  if (tid < 256) lbin[tid] = 0;
  __syncthreads();
  int d = 0, lrank = 0;
  if (i < N) {
    d = cnt[i];
    if (d > 255) d = 255;
    lrank = atomicAdd(&lbin[d], 1);
  }
  __syncthreads();
  if (tid < 256 && lbin[tid] > 0) lbase[tid] = atomicAdd(&dcur[tid], lbin[tid]);
  __syncthreads();
  if (i < N) perm[dstart[d] + lbase[d] + lrank] = i;
}

// ---------------- bucket edges by dst (CSR) ----------------
__global__ void scatter_kernel(const int* __restrict__ src,
                               const int* __restrict__ dst,
                               const int* __restrict__ row_start,
                               int* __restrict__ cursor,
                               int* __restrict__ csr_src, int E, int N) {
  int e = blockIdx.x * blockDim.x + threadIdx.x;
  if (e < E) {
    int d = dst[e];
    if ((unsigned)d < (unsigned)N) {
      int pos = row_start[d] + atomicAdd(&cursor[d], 1);
      int s = src[e];
      if ((unsigned)s >= (unsigned)N) s = 0;
      csr_src[pos] = s;
    }
  }
}

// ===== fused layer (degree-balanced): block handles 64 perm-consecutive
// nodes (equal degree) -> zero gather divergence. Gather: lane=(slot,oct),
// slot owns a node, 8 lanes read its neighbors' 128B rows, x4 edge unroll.
__global__ __launch_bounds__(256) void layer_kernel(
    const unsigned short* __restrict__ hin, unsigned short* __restrict__ hout,
    const int* __restrict__ row_start, const int* __restrict__ csr_src,
    const float* __restrict__ inv_deg, const int* __restrict__ perm,
    const unsigned short* __restrict__ Wlt,
    const unsigned short* __restrict__ Wrt, const float* __restrict__ bl,
    const float* __restrict__ Wc, const float* __restrict__ bc,
    float* __restrict__ out, int N) {
  __shared__ uint4 sAgg[512];  // 8 KB agg tile
  __shared__ uint4 sH[512];    // 8 KB own h rows
  __shared__ uint4 sWl[512];   // 8 KB Wl^T bf16
  __shared__ uint4 sWr[512];   // 8 KB Wr^T bf16
  __shared__ int sPerm[64];
  const int tid = threadIdx.x;
  const int lane = tid & 63;
  const int wid = tid >> 6;
  const int m15 = lane & 15;
  const int quad = lane >> 4;
  const int blockBase = blockIdx.x * 64;

  if (tid < 64) sPerm[tid] = (blockBase + tid < N) ? perm[blockBase + tid] : -1;
  __syncthreads();

  // ---- stage own h rows + both weight mats ----
  {
    const int r = tid >> 2;
    const int gp = tid & 3;
    const int g0 = gp * 2, g1 = gp * 2 + 1;
    const int u0 = r * 8 + (g0 ^ (r & 7));
    const int u1 = r * 8 + (g1 ^ (r & 7));
    const int gn = sPerm[r];
    if (gn >= 0) {
      const uint4* hp = (const uint4*)(hin + (size_t)gn * HID);
      sH[u0] = hp[g0];
      sH[u1] = hp[g1];
    } else {
      const uint4 z = make_uint4(0, 0, 0, 0);
      sH[u0] = z;
      sH[u1] = z;
    }
    const uint4* wl = (const uint4*)(Wlt + (size_t)r * HID);
    const uint4* wr = (const uint4*)(Wrt + (size_t)r * HID);
    sWl[u0] = wl[g0];
    sWl[u1] = wl[g1];
    sWr[u0] = wr[g0];
    sWr[u1] = wr[g1];
  }

  // ---- mean-aggregate neighbors into sAgg ----
  {
    const int slot = lane >> 3;  // 0..7: node slot
    const int oct = lane & 7;    // 0..7: uint4 column group (8 bf16)
#pragma unroll
    for (int g = 0; g < 2; g++) {
      const int nl = wid * 16 + g * 8 + slot;
      const int gn = sPerm[nl];
      float a0 = 0.f, a1 = 0.f, a2 = 0.f, a3 = 0.f, a4 = 0.f, a5 = 0.f,
            a6 = 0.f, a7 = 0.f;
      float id = 0.f;
      if (gn >= 0) {
        id = inv_deg[gn];
        const int s = row_start[gn];
        const int e = row_start[gn + 1];
        int j = s;
        for (; j + 4 <= e; j += 4) {
          const int n0 = csr_src[j];
          const int n1 = csr_src[j + 1];
          const int n2 = csr_src[j + 2];
          const int n3 = csr_src[j + 3];
          const uint4 v0 = *(const uint4*)(hin + (size_t)n0 * HID + oct * 8);
          const uint4 v1 = *(const uint4*)(hin + (size_t)n1 * HID + oct * 8);
          const uint4 v2 = *(const uint4*)(hin + (size_t)n2 * HID + oct * 8);
          const uint4 v3 = *(const uint4*)(hin + (size_t)n3 * HID + oct * 8);
          a0 += bflo(v0.x) + bflo(v1.x) + bflo(v2.x) + bflo(v3.x);
          a1 += bfhi(v0.x) + bfhi(v1.x) + bfhi(v2.x) + bfhi(v3.x);
          a2 += bflo(v0.y) + bflo(v1.y) + bflo(v2.y) + bflo(v3.y);
          a3 += bfhi(v0.y) + bfhi(v1.y) + bfhi(v2.y) + bfhi(v3.y);
          a4 += bflo(v0.z) + bflo(v1.z) + bflo(v2.z) + bflo(v3.z);
          a5 += bfhi(v0.z) + bfhi(v1.z) + bfhi(v2.z) + bfhi(v3.z);
          a6 += bflo(v0.w) + bflo(v1.w) + bflo(v2.w) + bflo(v3.w);
          a7 += bfhi(v0.w) + bfhi(v1.w) + bfhi(v2.w) + bfhi(v3.w);
        }
        for (; j < e; j++) {
          const int nb = csr_src[j];
          const uint4 v = *(const uint4*)(hin + (size_t)nb * HID + oct * 8);
          a0 += bflo(v.x);
          a1 += bfhi(v.x);
          a2 += bflo(v.y);
          a3 += bfhi(v.y);
          a4 += bflo(v.z);
          a5 += bfhi(v.z);
          a6 += bflo(v.w);
          a7 += bfhi(v.w);
        }
      }
      uint4 p;
      p.x = bf16pair(a0 * id, a1 * id);
      p.y = bf16pair(a2 * id, a3 * id);
      p.z = bf16pair(a4 * id, a5 * id);
      p.w = bf16pair(a6 * id, a7 * id);
      sAgg[nl * 8 + (oct ^ (nl & 7))] = p;
    }
  }
  __syncthreads();

  // ---- MFMA: acc = agg@Wl + h@Wr ----
  floatx4 acc[4];
#pragma unroll
  for (int c4 = 0; c4 < 4; c4++)
#pragma unroll
    for (int j = 0; j < 4; j++) acc[c4][j] = 0.f;

  const int arow = wid * 16 + m15;
#pragma unroll
  for (int c = 0; c < 2; c++) {
    const int ua = arow * 8 + ((c * 4 + quad) ^ (arow & 7));
    const short8 aA = __builtin_bit_cast(short8, sAgg[ua]);
    const short8 aH = __builtin_bit_cast(short8, sH[ua]);
#pragma unroll
    for (int c4 = 0; c4 < 4; c4++) {
      const int col = c4 * 16 + m15;
      const int ub = col * 8 + ((c * 4 + quad) ^ (col & 7));
      acc[c4] = __builtin_amdgcn_mfma_f32_16x16x32_bf16(
          aA, __builtin_bit_cast(short8, sWl[ub]), acc[c4], 0, 0, 0);
      acc[c4] = __builtin_amdgcn_mfma_f32_16x16x32_bf16(
          aH, __builtin_bit_cast(short8, sWr[ub]), acc[c4], 0, 0, 0);
    }
  }

  // ---- epilogue: residual + bias + relu; bf16 store; optional cls ----
  float vals[4][4];
#pragma unroll
  for (int c4 = 0; c4 < 4; c4++) {
    const float bias = bl[c4 * 16 + m15];
#pragma unroll
    for (int r = 0; r < 4; r++) {
      const int rowl = wid * 16 + quad * 4 + r;
      const unsigned short hv =
          ((const unsigned short*)
               sH)[(rowl * 8 + ((c4 * 2 + (m15 >> 3)) ^ (rowl & 7))) * 8 +
                   (m15 & 7)];
      const float v = __uint_as_float((unsigned)hv << 16) + acc[c4][r] + bias;
      vals[c4][r] = v > 0.f ? v : 0.f;
    }
  }
#pragma unroll
  for (int c4 = 0; c4 < 4; c4++) {
#pragma unroll
    for (int r = 0; r < 4; r++) {
      const int rowl = wid * 16 + quad * 4 + r;
      const int gn = sPerm[rowl];
      if (gn >= 0)
        hout[(size_t)gn * HID + c4 * 16 + m15] = bf16one(vals[c4][r]);
    }
  }
  if (Wc != nullptr) {
    float p[4] = {0.f, 0.f, 0.f, 0.f};
#pragma unroll
    for (int c4 = 0; c4 < 4; c4++) {
      const float wc = Wc[c4 * 16 + m15];
#pragma unroll
      for (int r = 0; r < 4; r++) p[r] += vals[c4][r] * wc;
    }
#pragma unroll
    for (int off = 1; off < 16; off <<= 1) {
#pragma unroll
      for (int r = 0; r < 4; r++) p[r] += __shfl_xor(p[r], off, 16);
    }
    if (m15 == 0) {
      const float bb = bc[0];
#pragma unroll
      for (int r = 0; r < 4; r++) {
        const int rowl = wid * 16 + quad * 4 + r;
        const int gn = sPerm[rowl];
        if (gn >= 0) out[gn] = 1.0f / (1.0f + expf(-(p[r] + bb)));
      }
    }
  }
}

extern "C" void kernel_launch(void* const* d_in, const int* in_sizes, int n_in,
                              void* d_out, int out_size, void* d_ws,
                              size_t ws_size, hipStream_t stream) {
  const float* x = (const float*)d_in[0];
  const int* ei = (const int*)d_in[1];
  const float* W_enc = (const float*)d_in[2];
  const float* b_enc = (const float*)d_in[3];
  const float* Wl = (const float*)d_in[4];
  const float* bl = (const float*)d_in[5];
  const float* Wr = (const float*)d_in[6];
  const float* Wc = (const float*)d_in[7];
  const float* bc = (const float*)d_in[8];
  float* out = (float*)d_out;

  const int N = in_sizes[0] / KIN;
  const int E = in_sizes[1] / 2;
  const int* src = ei;
  const int* dst = ei + E;

  char* ws = (char*)d_ws;
  size_t off = 0;
  auto alloc = [&](size_t bytes) -> void* {
    void* p = ws + off;
    off += (bytes + 255) & ~(size_t)255;
    return p;
  };
  unsigned short* hb0 =
      (unsigned short*)alloc((size_t)N * HID * sizeof(unsigned short));
  unsigned short* hb1 =
      (unsigned short*)alloc((size_t)N * HID * sizeof(unsigned short));
  // zero-init region: cnt, cursor, dbin, dcur (single memset)
  char* zbase = ws + off;
  int* cnt = (int*)alloc((size_t)N * sizeof(int));
  int* cursor = (int*)alloc((size_t)N * sizeof(int));
  int* dbin = (int*)alloc(256 * sizeof(int));
  int* dcur = (int*)alloc(256 * sizeof(int));
  const size_t zbytes = (ws + off) - zbase;
  int* row_start = (int*)alloc((size_t)(N + 1) * sizeof(int));
  float* inv_deg = (float*)alloc((size_t)N * sizeof(float));
  int* csr_src = (int*)alloc((size_t)E * sizeof(int));
  int* perm = (int*)alloc((size_t)N * sizeof(int));
  int* dstart = (int*)alloc(256 * sizeof(int));
  const int nblk = (N + 1023) / 1024;
  int* block_sums = (int*)alloc((size_t)nblk * sizeof(int));
  unsigned short* wte =
      (unsigned short*)alloc((size_t)HID * KIN * sizeof(unsigned short));
  unsigned short* wlrt =
      (unsigned short*)alloc((size_t)6 * HID * HID * sizeof(unsigned short));

  hipMemsetAsync(zbase, 0, zbytes, stream);

  prep_kernel<<<224, 256, 0, stream>>>(W_enc, Wl, Wr, wte, wlrt);
  hist_kernel<<<(E + 255) / 256, 256, 0, stream>>>(dst, cnt, E, N);
  scanA_kernel<<<nblk, 1024, 0, stream>>>(cnt, block_sums, N);
  scanB_kernel<<<1, 128, 0, stream>>>(block_sums, row_start, nblk, N);
  scanC_kernel<<<nblk, 1024, 0, stream>>>(cnt, block_sums, row_start, inv_deg,
                                          dbin, N);
  dscan_kernel<<<1, 256, 0, stream>>>(dbin, dstart);
  dscatter_kernel<<<nblk, 1024, 0, stream>>>(cnt, dstart, dcur, perm, N);
  scatter_kernel<<<(E + 255) / 256, 256, 0, stream>>>(src, dst, row_start,
                                                      cursor, csr_src, E, N);
  enc_kernel<<<(N + 63) / 64, 256, 0, stream>>>(x, wte, b_enc, hb0, N);

  const int nb64 = (N + 63) / 64;
  // layer 0: hb0 -> hb1
  layer_kernel<<<nb64, 256, 0, stream>>>(hb0, hb1, row_start, csr_src, inv_deg,
                                         perm, wlrt, wlrt + 3 * 4096, bl,
                                         nullptr, nullptr, nullptr, N);
  // layer 1: hb1 -> hb0
  layer_kernel<<<nb64, 256, 0, stream>>>(hb1, hb0, row_start, csr_src, inv_deg,
                                         perm, wlrt + 4096, wlrt + 4 * 4096,
                                         bl + 64, nullptr, nullptr, nullptr, N);
  // layer 2: hb0 -> hb1, fused classifier
  layer_kernel<<<nb64, 256, 0, stream>>>(hb0, hb1, row_start, csr_src, inv_deg,
                                         perm, wlrt + 2 * 4096, wlrt + 5 * 4096,
                                         bl + 128, Wc, bc, out, N);
}

// Round 9
// 565.732 us; speedup vs baseline: 1.5115x; 1.5115x over previous
//
#include <hip/hip_runtime.h>
#include <math.h>

#define HID 64
#define KIN 512

typedef __attribute__((ext_vector_type(8))) short short8;   // 8 bf16 (4 VGPR)
typedef __attribute__((ext_vector_type(4))) float floatx4;  // MFMA acc

// RNE fp32 -> bf16
__device__ inline unsigned bf16pair(float a, float b) {
  unsigned ua = __float_as_uint(a);
  unsigned ub = __float_as_uint(b);
  ua = (ua + 0x7FFFu + ((ua >> 16) & 1u)) >> 16;
  ub = (ub + 0x7FFFu + ((ub >> 16) & 1u)) >> 16;
  return ua | (ub << 16);
}
__device__ inline unsigned short bf16one(float a) {
  unsigned ua = __float_as_uint(a);
  return (unsigned short)((ua + 0x7FFFu + ((ua >> 16) & 1u)) >> 16);
}
__device__ inline float bflo(unsigned u) { return __uint_as_float(u << 16); }
__device__ inline float bfhi(unsigned u) {
  return __uint_as_float(u & 0xffff0000u);
}

// ---- one-time weight prep: transpose + bf16 ----
__global__ __launch_bounds__(256) void prep_kernel(
    const float* __restrict__ We, const float* __restrict__ Wl,
    const float* __restrict__ Wr, unsigned short* __restrict__ wte,
    unsigned short* __restrict__ wlrt) {
  const int blk = blockIdx.x;
  const int tid = threadIdx.x;
  if (blk < 128) {
    const int t = blk * 256 + tid;
    const int c = t >> 9, k = t & 511;
    wte[c * KIN + k] = bf16one(We[k * HID + c]);
  } else {
    const int t = (blk - 128) * 256 + tid;  // 0..24575
    const int mat = t >> 12;                // 0..5
    const int e = t & 4095;
    const int c = e >> 6, k = e & 63;
    const float* src =
        (mat < 3) ? (Wl + (size_t)mat * 4096) : (Wr + (size_t)(mat - 3) * 4096);
    wlrt[(size_t)mat * 4096 + c * 64 + k] = bf16one(src[k * 64 + c]);
  }
}

// ---- encoder: hb = bf16(x @ W_enc + b_enc) via MFMA ----
__global__ __launch_bounds__(256) void enc_kernel(
    const float* __restrict__ x, const unsigned short* __restrict__ wt,
    const float* __restrict__ b, unsigned short* __restrict__ hb, int N) {
  __shared__ uint4 sx[2][256];
  __shared__ uint4 sw[2][256];
  const int t = threadIdx.x;
  const int lane = t & 63;
  const int wid = t >> 6;
  const int m15 = lane & 15;
  const int quad = lane >> 4;
  const int blockBase = blockIdx.x * 64;

  const int rs = t >> 2;
  const int qs = t & 3;
  const int us = rs * 4 + (qs ^ ((rs >> 1) & 3));
  const int gn = blockBase + rs;
  const bool valid = gn < N;
  const float* xp = x + (size_t)(valid ? gn : 0) * KIN + qs * 8;
  const unsigned short* wp = wt + (size_t)rs * KIN + qs * 8;

  const int arow = wid * 16 + m15;
  const int ua = arow * 4 + (quad ^ ((arow >> 1) & 3));
  int ub[4];
#pragma unroll
  for (int c4 = 0; c4 < 4; c4++) {
    const int col = c4 * 16 + m15;
    ub[c4] = col * 4 + (quad ^ ((col >> 1) & 3));
  }

  floatx4 acc[4];
#pragma unroll
  for (int c4 = 0; c4 < 4; c4++)
#pragma unroll
    for (int j = 0; j < 4; j++) acc[c4][j] = 0.f;

  float4 fx0, fx1;
  uint4 wv;
  if (valid) {
    fx0 = *(const float4*)(xp);
    fx1 = *(const float4*)(xp + 4);
  } else {
    fx0 = fx1 = make_float4(0.f, 0.f, 0.f, 0.f);
  }
  wv = *(const uint4*)(wp);

  for (int kc = 0; kc < 16; kc++) {
    const int cur = kc & 1;
    uint4 xu;
    xu.x = bf16pair(fx0.x, fx0.y);
    xu.y = bf16pair(fx0.z, fx0.w);
    xu.z = bf16pair(fx1.x, fx1.y);
    xu.w = bf16pair(fx1.z, fx1.w);
    sx[cur][us] = xu;
    sw[cur][us] = wv;
    __syncthreads();
    if (kc < 15) {
      const int ko = (kc + 1) * 32;
      if (valid) {
        fx0 = *(const float4*)(xp + ko);
        fx1 = *(const float4*)(xp + ko + 4);
      }
      wv = *(const uint4*)(wp + ko);
    }
    const short8 a = __builtin_bit_cast(short8, sx[cur][ua]);
#pragma unroll
    for (int c4 = 0; c4 < 4; c4++) {
      const short8 bf = __builtin_bit_cast(short8, sw[cur][ub[c4]]);
      acc[c4] =
          __builtin_amdgcn_mfma_f32_16x16x32_bf16(a, bf, acc[c4], 0, 0, 0);
    }
  }

#pragma unroll
  for (int c4 = 0; c4 < 4; c4++) {
    const float bias = b[c4 * 16 + m15];
#pragma unroll
    for (int r = 0; r < 4; r++) {
      const int row = blockBase + wid * 16 + quad * 4 + r;
      if (row < N)
        hb[(size_t)row * HID + c4 * 16 + m15] = bf16one(acc[c4][r] + bias);
    }
  }
}

// ---------------- degree histogram ----------------
__global__ void hist_kernel(const int* __restrict__ dst, int* __restrict__ cnt,
                            int E, int N) {
  int e = blockIdx.x * blockDim.x + threadIdx.x;
  if (e < E) {
    int d = dst[e];
    if ((unsigned)d < (unsigned)N) atomicAdd(&cnt[d], 1);
  }
}

// ---------------- parallel scan ----------------
__global__ __launch_bounds__(1024) void scanA_kernel(
    const int* __restrict__ cnt, int* __restrict__ block_sums, int N) {
  __shared__ int red[1024];
  const int tid = threadIdx.x;
  const int i = blockIdx.x * 1024 + tid;
  red[tid] = (i < N) ? cnt[i] : 0;
  __syncthreads();
  for (int off = 512; off > 0; off >>= 1) {
    if (tid < off) red[tid] += red[tid + off];
    __syncthreads();
  }
  if (tid == 0) block_sums[blockIdx.x] = red[0];
}

__global__ __launch_bounds__(128) void scanB_kernel(
    int* __restrict__ block_sums, int* __restrict__ row_start, int nblk,
    int N) {
  __shared__ int part[128];
  const int tid = threadIdx.x;
  part[tid] = (tid < nblk) ? block_sums[tid] : 0;
  __syncthreads();
  for (int off = 1; off < 128; off <<= 1) {
    int t = (tid >= off) ? part[tid - off] : 0;
    __syncthreads();
    part[tid] += t;
    __syncthreads();
  }
  if (tid < nblk) block_sums[tid] = (tid > 0) ? part[tid - 1] : 0;
  if (tid == 127) row_start[N] = part[127];
}

__global__ __launch_bounds__(1024) void scanC_kernel(
    const int* __restrict__ cnt, const int* __restrict__ block_sums,
    int* __restrict__ row_start, float* __restrict__ inv_deg, int N) {
  __shared__ int part[1024];
  const int tid = threadIdx.x;
  const int i = blockIdx.x * 1024 + tid;
  const int v = (i < N) ? cnt[i] : 0;
  part[tid] = v;
  __syncthreads();
  for (int off = 1; off < 1024; off <<= 1) {
    int t = (tid >= off) ? part[tid - off] : 0;
    __syncthreads();
    part[tid] += t;
    __syncthreads();
  }
  if (i < N) {
    row_start[i] = block_sums[blockIdx.x] + part[tid] - v;
    inv_deg[i] = (v > 0) ? 1.0f / (float)v : 0.0f;
  }
}

// ---------------- bucket edges by dst (CSR) ----------------
__global__ void scatter_kernel(const int* __restrict__ src,
                               const int* __restrict__ dst,
                               const int* __restrict__ row_start,
                               int* __restrict__ cursor,
                               int* __restrict__ csr_src, int E, int N) {
  int e = blockIdx.x * blockDim.x + threadIdx.x;
  if (e < E) {
    int d = dst[e];
    if ((unsigned)d < (unsigned)N) {
      int pos = row_start[d] + atomicAdd(&cursor[d], 1);
      int s = src[e];
      if ((unsigned)s >= (unsigned)N) s = 0;
      csr_src[pos] = s;
    }
  }
}

// ===== fused layer: gather-mean -> [agg|h]@[Wl;Wr] MFMA -> residual/relu
//       -> bf16 store (+ optional classifier on last layer) =====
// Gather: lane=(slot 0..7, oct 0..7); slot owns a node. Edge loop runs in
// masked x8 steps: 8 idx loads + 8 independent 16B row-gathers in flight per
// lane, out-of-range steps cndmask'd to zero -> NO serial remainder chain.
__global__ __launch_bounds__(256) void layer_kernel(
    const unsigned short* __restrict__ hin, unsigned short* __restrict__ hout,
    const int* __restrict__ row_start, const int* __restrict__ csr_src,
    const float* __restrict__ inv_deg, const unsigned short* __restrict__ Wlt,
    const unsigned short* __restrict__ Wrt, const float* __restrict__ bl,
    const float* __restrict__ Wc, const float* __restrict__ bc,
    float* __restrict__ out, int N) {
  __shared__ uint4 sAgg[512];  // 8 KB agg tile
  __shared__ uint4 sH[512];    // 8 KB own h rows
  __shared__ uint4 sWl[512];   // 8 KB Wl^T bf16
  __shared__ uint4 sWr[512];   // 8 KB Wr^T bf16
  const int tid = threadIdx.x;
  const int lane = tid & 63;
  const int wid = tid >> 6;
  const int m15 = lane & 15;
  const int quad = lane >> 4;
  const int blockBase = blockIdx.x * 64;

  // ---- stage own h rows + both weight mats ----
  {
    const int r = tid >> 2;
    const int gp = tid & 3;
    const int g0 = gp * 2, g1 = gp * 2 + 1;
    const int u0 = r * 8 + (g0 ^ (r & 7));
    const int u1 = r * 8 + (g1 ^ (r & 7));
    const int gn = blockBase + r;
    if (gn < N) {
      const uint4* hp = (const uint4*)(hin + (size_t)gn * HID);
      sH[u0] = hp[g0];
      sH[u1] = hp[g1];
    } else {
      const uint4 z = make_uint4(0, 0, 0, 0);
      sH[u0] = z;
      sH[u1] = z;
    }
    const uint4* wl = (const uint4*)(Wlt + (size_t)r * HID);
    const uint4* wr = (const uint4*)(Wrt + (size_t)r * HID);
    sWl[u0] = wl[g0];
    sWl[u1] = wl[g1];
    sWr[u0] = wr[g0];
    sWr[u1] = wr[g1];
  }

  // ---- mean-aggregate neighbors into sAgg ----
  {
    const int slot = lane >> 3;  // 0..7: node slot
    const int oct = lane & 7;    // 0..7: uint4 column group (8 bf16)
#pragma unroll
    for (int g = 0; g < 2; g++) {
      const int nl = wid * 16 + g * 8 + slot;
      const int gn = blockBase + nl;
      float a0 = 0.f, a1 = 0.f, a2 = 0.f, a3 = 0.f, a4 = 0.f, a5 = 0.f,
            a6 = 0.f, a7 = 0.f;
      float id = 0.f;
      if (gn < N) {
        id = inv_deg[gn];
        const int s = row_start[gn];
        const int e = row_start[gn + 1];
        for (int j = s; j < e; j += 8) {
          int n[8];
          bool ok[8];
#pragma unroll
          for (int u = 0; u < 8; u++) {
            const int jj = j + u;
            ok[u] = jj < e;
            n[u] = csr_src[ok[u] ? jj : j];
          }
          uint4 v[8];
#pragma unroll
          for (int u = 0; u < 8; u++) {
            v[u] = *(const uint4*)(hin + (size_t)n[u] * HID + oct * 8);
          }
#pragma unroll
          for (int u = 0; u < 8; u++) {
            if (!ok[u]) v[u] = make_uint4(0, 0, 0, 0);
            a0 += bflo(v[u].x);
            a1 += bfhi(v[u].x);
            a2 += bflo(v[u].y);
            a3 += bfhi(v[u].y);
            a4 += bflo(v[u].z);
            a5 += bfhi(v[u].z);
            a6 += bflo(v[u].w);
            a7 += bfhi(v[u].w);
          }
        }
      }
      uint4 p;
      p.x = bf16pair(a0 * id, a1 * id);
      p.y = bf16pair(a2 * id, a3 * id);
      p.z = bf16pair(a4 * id, a5 * id);
      p.w = bf16pair(a6 * id, a7 * id);
      sAgg[nl * 8 + (oct ^ (nl & 7))] = p;
    }
  }
  __syncthreads();

  // ---- MFMA: acc = agg@Wl + h@Wr ----
  floatx4 acc[4];
#pragma unroll
  for (int c4 = 0; c4 < 4; c4++)
#pragma unroll
    for (int j = 0; j < 4; j++) acc[c4][j] = 0.f;

  const int arow = wid * 16 + m15;
#pragma unroll
  for (int c = 0; c < 2; c++) {
    const int ua = arow * 8 + ((c * 4 + quad) ^ (arow & 7));
    const short8 aA = __builtin_bit_cast(short8, sAgg[ua]);
    const short8 aH = __builtin_bit_cast(short8, sH[ua]);
#pragma unroll
    for (int c4 = 0; c4 < 4; c4++) {
      const int col = c4 * 16 + m15;
      const int ub = col * 8 + ((c * 4 + quad) ^ (col & 7));
      acc[c4] = __builtin_amdgcn_mfma_f32_16x16x32_bf16(
          aA, __builtin_bit_cast(short8, sWl[ub]), acc[c4], 0, 0, 0);
      acc[c4] = __builtin_amdgcn_mfma_f32_16x16x32_bf16(
          aH, __builtin_bit_cast(short8, sWr[ub]), acc[c4], 0, 0, 0);
    }
  }

  // ---- epilogue: residual + bias + relu; bf16 store; optional cls ----
  float vals[4][4];
#pragma unroll
  for (int c4 = 0; c4 < 4; c4++) {
    const float bias = bl[c4 * 16 + m15];
#pragma unroll
    for (int r = 0; r < 4; r++) {
      const int rowl = wid * 16 + quad * 4 + r;
      const unsigned short hv =
          ((const unsigned short*)
               sH)[(rowl * 8 + ((c4 * 2 + (m15 >> 3)) ^ (rowl & 7))) * 8 +
                   (m15 & 7)];
      const float v = __uint_as_float((unsigned)hv << 16) + acc[c4][r] + bias;
      vals[c4][r] = v > 0.f ? v : 0.f;
    }
  }
#pragma unroll
  for (int c4 = 0; c4 < 4; c4++) {
#pragma unroll
    for (int r = 0; r < 4; r++) {
      const int rowg = blockBase + wid * 16 + quad * 4 + r;
      if (rowg < N)
        hout[(size_t)rowg * HID + c4 * 16 + m15] = bf16one(vals[c4][r]);
    }
  }
  if (Wc != nullptr) {
    float p[4] = {0.f, 0.f, 0.f, 0.f};
#pragma unroll
    for (int c4 = 0; c4 < 4; c4++) {
      const float wc = Wc[c4 * 16 + m15];
#pragma unroll
      for (int r = 0; r < 4; r++) p[r] += vals[c4][r] * wc;
    }
#pragma unroll
    for (int off = 1; off < 16; off <<= 1) {
#pragma unroll
      for (int r = 0; r < 4; r++) p[r] += __shfl_xor(p[r], off, 16);
    }
    if (m15 == 0) {
      const float bb = bc[0];
#pragma unroll
      for (int r = 0; r < 4; r++) {
        const int rowg = blockBase + wid * 16 + quad * 4 + r;
        if (rowg < N) out[rowg] = 1.0f / (1.0f + expf(-(p[r] + bb)));
      }
    }
  }
}

extern "C" void kernel_launch(void* const* d_in, const int* in_sizes, int n_in,
                              void* d_out, int out_size, void* d_ws,
                              size_t ws_size, hipStream_t stream) {
  const float* x = (const float*)d_in[0];
  const int* ei = (const int*)d_in[1];
  const float* W_enc = (const float*)d_in[2];
  const float* b_enc = (const float*)d_in[3];
  const float* Wl = (const float*)d_in[4];
  const float* bl = (const float*)d_in[5];
  const float* Wr = (const float*)d_in[6];
  const float* Wc = (const float*)d_in[7];
  const float* bc = (const float*)d_in[8];
  float* out = (float*)d_out;

  const int N = in_sizes[0] / KIN;
  const int E = in_sizes[1] / 2;
  const int* src = ei;
  const int* dst = ei + E;

  char* ws = (char*)d_ws;
  size_t off = 0;
  auto alloc = [&](size_t bytes) -> void* {
    void* p = ws + off;
    off += (bytes + 255) & ~(size_t)255;
    return p;
  };
  unsigned short* hb0 =
      (unsigned short*)alloc((size_t)N * HID * sizeof(unsigned short));
  unsigned short* hb1 =
      (unsigned short*)alloc((size_t)N * HID * sizeof(unsigned short));
  // zero-init region: cnt, cursor (single memset)
  char* zbase = ws + off;
  int* cnt = (int*)alloc((size_t)N * sizeof(int));
  int* cursor = (int*)alloc((size_t)N * sizeof(int));
  const size_t zbytes = (ws + off) - zbase;
  int* row_start = (int*)alloc((size_t)(N + 1) * sizeof(int));
  float* inv_deg = (float*)alloc((size_t)N * sizeof(float));
  int* csr_src = (int*)alloc((size_t)E * sizeof(int));
  const int nblk = (N + 1023) / 1024;
  int* block_sums = (int*)alloc((size_t)nblk * sizeof(int));
  unsigned short* wte =
      (unsigned short*)alloc((size_t)HID * KIN * sizeof(unsigned short));
  unsigned short* wlrt =
      (unsigned short*)alloc((size_t)6 * HID * HID * sizeof(unsigned short));

  hipMemsetAsync(zbase, 0, zbytes, stream);

  prep_kernel<<<224, 256, 0, stream>>>(W_enc, Wl, Wr, wte, wlrt);
  hist_kernel<<<(E + 255) / 256, 256, 0, stream>>>(dst, cnt, E, N);
  scanA_kernel<<<nblk, 1024, 0, stream>>>(cnt, block_sums, N);
  scanB_kernel<<<1, 128, 0, stream>>>(block_sums, row_start, nblk, N);
  scanC_kernel<<<nblk, 1024, 0, stream>>>(cnt, block_sums, row_start, inv_deg,
                                          N);
  scatter_kernel<<<(E + 255) / 256, 256, 0, stream>>>(src, dst, row_start,
                                                      cursor, csr_src, E, N);
  enc_kernel<<<(N + 63) / 64, 256, 0, stream>>>(x, wte, b_enc, hb0, N);

  const int nb64 = (N + 63) / 64;
  // layer 0: hb0 -> hb1
  layer_kernel<<<nb64, 256, 0, stream>>>(hb0, hb1, row_start, csr_src, inv_deg,
                                         wlrt, wlrt + 3 * 4096, bl, nullptr,
                                         nullptr, nullptr, N);
  // layer 1: hb1 -> hb0
  layer_kernel<<<nb64, 256, 0, stream>>>(hb1, hb0, row_start, csr_src, inv_deg,
                                         wlrt + 4096, wlrt + 4 * 4096, bl + 64,
                                         nullptr, nullptr, nullptr, N);
  // layer 2: hb0 -> hb1, fused classifier
  layer_kernel<<<nb64, 256, 0, stream>>>(hb0, hb1, row_start, csr_src, inv_deg,
                                         wlrt + 2 * 4096, wlrt + 5 * 4096,
                                         bl + 128, Wc, bc, out, N);
}

// Round 10
// 561.819 us; speedup vs baseline: 1.5220x; 1.0070x over previous
//
#include <hip/hip_runtime.h>
#include <math.h>

#define HID 64
#define KIN 512

typedef __attribute__((ext_vector_type(8))) short short8;   // 8 bf16 (4 VGPR)
typedef __attribute__((ext_vector_type(4))) float floatx4;  // MFMA acc

// RNE fp32 -> bf16
__device__ inline unsigned bf16pair(float a, float b) {
  unsigned ua = __float_as_uint(a);
  unsigned ub = __float_as_uint(b);
  ua = (ua + 0x7FFFu + ((ua >> 16) & 1u)) >> 16;
  ub = (ub + 0x7FFFu + ((ub >> 16) & 1u)) >> 16;
  return ua | (ub << 16);
}
__device__ inline unsigned short bf16one(float a) {
  unsigned ua = __float_as_uint(a);
  return (unsigned short)((ua + 0x7FFFu + ((ua >> 16) & 1u)) >> 16);
}
// fp8 e4m3 (OCP) quantize one float -> byte, via HW pack cvt
__device__ inline unsigned char fp8q(float a) {
  const int pk = __builtin_amdgcn_cvt_pk_fp8_f32(a, a, 0, false);
  return (unsigned char)(pk & 0xff);
}

// ---- one-time weight prep: transpose + bf16 ----
__global__ __launch_bounds__(256) void prep_kernel(
    const float* __restrict__ We, const float* __restrict__ Wl,
    const float* __restrict__ Wr, unsigned short* __restrict__ wte,
    unsigned short* __restrict__ wlrt) {
  const int blk = blockIdx.x;
  const int tid = threadIdx.x;
  if (blk < 128) {
    const int t = blk * 256 + tid;
    const int c = t >> 9, k = t & 511;
    wte[c * KIN + k] = bf16one(We[k * HID + c]);
  } else {
    const int t = (blk - 128) * 256 + tid;  // 0..24575
    const int mat = t >> 12;                // 0..5
    const int e = t & 4095;
    const int c = e >> 6, k = e & 63;
    const float* src =
        (mat < 3) ? (Wl + (size_t)mat * 4096) : (Wr + (size_t)(mat - 3) * 4096);
    wlrt[(size_t)mat * 4096 + c * 64 + k] = bf16one(src[k * 64 + c]);
  }
}

// ---- encoder: hb = bf16(x @ W_enc + b_enc); also fp8 copy h8 ----
__global__ __launch_bounds__(256) void enc_kernel(
    const float* __restrict__ x, const unsigned short* __restrict__ wt,
    const float* __restrict__ b, unsigned short* __restrict__ hb,
    unsigned char* __restrict__ h8, int N) {
  __shared__ uint4 sx[2][256];
  __shared__ uint4 sw[2][256];
  const int t = threadIdx.x;
  const int lane = t & 63;
  const int wid = t >> 6;
  const int m15 = lane & 15;
  const int quad = lane >> 4;
  const int blockBase = blockIdx.x * 64;

  const int rs = t >> 2;
  const int qs = t & 3;
  const int us = rs * 4 + (qs ^ ((rs >> 1) & 3));
  const int gn = blockBase + rs;
  const bool valid = gn < N;
  const float* xp = x + (size_t)(valid ? gn : 0) * KIN + qs * 8;
  const unsigned short* wp = wt + (size_t)rs * KIN + qs * 8;

  const int arow = wid * 16 + m15;
  const int ua = arow * 4 + (quad ^ ((arow >> 1) & 3));
  int ub[4];
#pragma unroll
  for (int c4 = 0; c4 < 4; c4++) {
    const int col = c4 * 16 + m15;
    ub[c4] = col * 4 + (quad ^ ((col >> 1) & 3));
  }

  floatx4 acc[4];
#pragma unroll
  for (int c4 = 0; c4 < 4; c4++)
#pragma unroll
    for (int j = 0; j < 4; j++) acc[c4][j] = 0.f;

  float4 fx0, fx1;
  uint4 wv;
  if (valid) {
    fx0 = *(const float4*)(xp);
    fx1 = *(const float4*)(xp + 4);
  } else {
    fx0 = fx1 = make_float4(0.f, 0.f, 0.f, 0.f);
  }
  wv = *(const uint4*)(wp);

  for (int kc = 0; kc < 16; kc++) {
    const int cur = kc & 1;
    uint4 xu;
    xu.x = bf16pair(fx0.x, fx0.y);
    xu.y = bf16pair(fx0.z, fx0.w);
    xu.z = bf16pair(fx1.x, fx1.y);
    xu.w = bf16pair(fx1.z, fx1.w);
    sx[cur][us] = xu;
    sw[cur][us] = wv;
    __syncthreads();
    if (kc < 15) {
      const int ko = (kc + 1) * 32;
      if (valid) {
        fx0 = *(const float4*)(xp + ko);
        fx1 = *(const float4*)(xp + ko + 4);
      }
      wv = *(const uint4*)(wp + ko);
    }
    const short8 a = __builtin_bit_cast(short8, sx[cur][ua]);
#pragma unroll
    for (int c4 = 0; c4 < 4; c4++) {
      const short8 bf = __builtin_bit_cast(short8, sw[cur][ub[c4]]);
      acc[c4] =
          __builtin_amdgcn_mfma_f32_16x16x32_bf16(a, bf, acc[c4], 0, 0, 0);
    }
  }

#pragma unroll
  for (int c4 = 0; c4 < 4; c4++) {
    const float bias = b[c4 * 16 + m15];
#pragma unroll
    for (int r = 0; r < 4; r++) {
      const int row = blockBase + wid * 16 + quad * 4 + r;
      if (row < N) {
        const float v = acc[c4][r] + bias;
        hb[(size_t)row * HID + c4 * 16 + m15] = bf16one(v);
        h8[(size_t)row * HID + c4 * 16 + m15] = fp8q(v);
      }
    }
  }
}

// ---------------- degree histogram ----------------
__global__ void hist_kernel(const int* __restrict__ dst, int* __restrict__ cnt,
                            int E, int N) {
  int e = blockIdx.x * blockDim.x + threadIdx.x;
  if (e < E) {
    int d = dst[e];
    if ((unsigned)d < (unsigned)N) atomicAdd(&cnt[d], 1);
  }
}

// ---------------- parallel scan ----------------
__global__ __launch_bounds__(1024) void scanA_kernel(
    const int* __restrict__ cnt, int* __restrict__ block_sums, int N) {
  __shared__ int red[1024];
  const int tid = threadIdx.x;
  const int i = blockIdx.x * 1024 + tid;
  red[tid] = (i < N) ? cnt[i] : 0;
  __syncthreads();
  for (int off = 512; off > 0; off >>= 1) {
    if (tid < off) red[tid] += red[tid + off];
    __syncthreads();
  }
  if (tid == 0) block_sums[blockIdx.x] = red[0];
}

__global__ __launch_bounds__(128) void scanB_kernel(
    int* __restrict__ block_sums, int* __restrict__ row_start, int nblk,
    int N) {
  __shared__ int part[128];
  const int tid = threadIdx.x;
  part[tid] = (tid < nblk) ? block_sums[tid] : 0;
  __syncthreads();
  for (int off = 1; off < 128; off <<= 1) {
    int t = (tid >= off) ? part[tid - off] : 0;
    __syncthreads();
    part[tid] += t;
    __syncthreads();
  }
  if (tid < nblk) block_sums[tid] = (tid > 0) ? part[tid - 1] : 0;
  if (tid == 127) row_start[N] = part[127];
}

__global__ __launch_bounds__(1024) void scanC_kernel(
    const int* __restrict__ cnt, const int* __restrict__ block_sums,
    int* __restrict__ row_start, float* __restrict__ inv_deg, int N) {
  __shared__ int part[1024];
  const int tid = threadIdx.x;
  const int i = blockIdx.x * 1024 + tid;
  const int v = (i < N) ? cnt[i] : 0;
  part[tid] = v;
  __syncthreads();
  for (int off = 1; off < 1024; off <<= 1) {
    int t = (tid >= off) ? part[tid - off] : 0;
    __syncthreads();
    part[tid] += t;
    __syncthreads();
  }
  if (i < N) {
    row_start[i] = block_sums[blockIdx.x] + part[tid] - v;
    inv_deg[i] = (v > 0) ? 1.0f / (float)v : 0.0f;
  }
}

// ---------------- bucket edges by dst (CSR) ----------------
__global__ void scatter_kernel(const int* __restrict__ src,
                               const int* __restrict__ dst,
                               const int* __restrict__ row_start,
                               int* __restrict__ cursor,
                               int* __restrict__ csr_src, int E, int N) {
  int e = blockIdx.x * blockDim.x + threadIdx.x;
  if (e < E) {
    int d = dst[e];
    if ((unsigned)d < (unsigned)N) {
      int pos = row_start[d] + atomicAdd(&cursor[d], 1);
      int s = src[e];
      if ((unsigned)s >= (unsigned)N) s = 0;
      csr_src[pos] = s;
    }
  }
}

// ===== fused layer: fp8 gather-mean -> [agg|h]@[Wl;Wr] MFMA -> residual/relu
//       -> bf16(+fp8) store (+ optional classifier on last layer) =====
// Gather: lane=(slot 0..15, qc 0..3); slot owns a node; 4 lanes read its
// neighbor's 64B fp8 row. x8 masked unroll: 8 idx + 8 row-gathers in flight
// per lane; wave covers 16 nodes concurrently. HW v_cvt_f32_fp8 dequant.
__global__ __launch_bounds__(256) void layer_kernel(
    const unsigned short* __restrict__ hin,
    const unsigned char* __restrict__ h8in, unsigned short* __restrict__ hout,
    unsigned char* __restrict__ h8out, const int* __restrict__ row_start,
    const int* __restrict__ csr_src, const float* __restrict__ inv_deg,
    const unsigned short* __restrict__ Wlt,
    const unsigned short* __restrict__ Wrt, const float* __restrict__ bl,
    const float* __restrict__ Wc, const float* __restrict__ bc,
    float* __restrict__ out, int N) {
  __shared__ uint4 sAgg[512];  // 8 KB agg tile (bf16)
  __shared__ uint4 sH[512];    // 8 KB own h rows (bf16)
  __shared__ uint4 sWl[512];   // 8 KB Wl^T bf16
  __shared__ uint4 sWr[512];   // 8 KB Wr^T bf16
  const int tid = threadIdx.x;
  const int lane = tid & 63;
  const int wid = tid >> 6;
  const int m15 = lane & 15;
  const int quad = lane >> 4;
  const int blockBase = blockIdx.x * 64;

  // ---- stage own h rows + both weight mats ----
  {
    const int r = tid >> 2;
    const int gp = tid & 3;
    const int g0 = gp * 2, g1 = gp * 2 + 1;
    const int u0 = r * 8 + (g0 ^ (r & 7));
    const int u1 = r * 8 + (g1 ^ (r & 7));
    const int gn = blockBase + r;
    if (gn < N) {
      const uint4* hp = (const uint4*)(hin + (size_t)gn * HID);
      sH[u0] = hp[g0];
      sH[u1] = hp[g1];
    } else {
      const uint4 z = make_uint4(0, 0, 0, 0);
      sH[u0] = z;
      sH[u1] = z;
    }
    const uint4* wl = (const uint4*)(Wlt + (size_t)r * HID);
    const uint4* wr = (const uint4*)(Wrt + (size_t)r * HID);
    sWl[u0] = wl[g0];
    sWl[u1] = wl[g1];
    sWr[u0] = wr[g0];
    sWr[u1] = wr[g1];
  }

  // ---- mean-aggregate neighbors (fp8 rows) into sAgg ----
  {
    const int slot = lane >> 2;  // 0..15: node slot
    const int qc = lane & 3;     // 0..3: 16B group (16 fp8 cols)
    const int nl = wid * 16 + slot;
    const int gn = blockBase + nl;
    float a[16];
#pragma unroll
    for (int c = 0; c < 16; c++) a[c] = 0.f;
    float id = 0.f;
    if (gn < N) {
      id = inv_deg[gn];
      const int s = row_start[gn];
      const int e = row_start[gn + 1];
      for (int j = s; j < e; j += 8) {
        int n[8];
        bool ok[8];
#pragma unroll
        for (int u = 0; u < 8; u++) {
          const int jj = j + u;
          ok[u] = jj < e;
          n[u] = csr_src[ok[u] ? jj : j];
        }
        uint4 v[8];
#pragma unroll
        for (int u = 0; u < 8; u++) {
          v[u] = *(const uint4*)(h8in + (size_t)n[u] * HID + qc * 16);
        }
#pragma unroll
        for (int u = 0; u < 8; u++) {
          if (!ok[u]) v[u] = make_uint4(0, 0, 0, 0);
          a[0] += __builtin_amdgcn_cvt_f32_fp8(v[u].x, 0);
          a[1] += __builtin_amdgcn_cvt_f32_fp8(v[u].x, 1);
          a[2] += __builtin_amdgcn_cvt_f32_fp8(v[u].x, 2);
          a[3] += __builtin_amdgcn_cvt_f32_fp8(v[u].x, 3);
          a[4] += __builtin_amdgcn_cvt_f32_fp8(v[u].y, 0);
          a[5] += __builtin_amdgcn_cvt_f32_fp8(v[u].y, 1);
          a[6] += __builtin_amdgcn_cvt_f32_fp8(v[u].y, 2);
          a[7] += __builtin_amdgcn_cvt_f32_fp8(v[u].y, 3);
          a[8] += __builtin_amdgcn_cvt_f32_fp8(v[u].z, 0);
          a[9] += __builtin_amdgcn_cvt_f32_fp8(v[u].z, 1);
          a[10] += __builtin_amdgcn_cvt_f32_fp8(v[u].z, 2);
          a[11] += __builtin_amdgcn_cvt_f32_fp8(v[u].z, 3);
          a[12] += __builtin_amdgcn_cvt_f32_fp8(v[u].w, 0);
          a[13] += __builtin_amdgcn_cvt_f32_fp8(v[u].w, 1);
          a[14] += __builtin_amdgcn_cvt_f32_fp8(v[u].w, 2);
          a[15] += __builtin_amdgcn_cvt_f32_fp8(v[u].w, 3);
        }
      }
    }
    uint4 p0, p1;
    p0.x = bf16pair(a[0] * id, a[1] * id);
    p0.y = bf16pair(a[2] * id, a[3] * id);
    p0.z = bf16pair(a[4] * id, a[5] * id);
    p0.w = bf16pair(a[6] * id, a[7] * id);
    p1.x = bf16pair(a[8] * id, a[9] * id);
    p1.y = bf16pair(a[10] * id, a[11] * id);
    p1.z = bf16pair(a[12] * id, a[13] * id);
    p1.w = bf16pair(a[14] * id, a[15] * id);
    sAgg[nl * 8 + ((qc * 2) ^ (nl & 7))] = p0;
    sAgg[nl * 8 + ((qc * 2 + 1) ^ (nl & 7))] = p1;
  }
  __syncthreads();

  // ---- MFMA: acc = agg@Wl + h@Wr ----
  floatx4 acc[4];
#pragma unroll
  for (int c4 = 0; c4 < 4; c4++)
#pragma unroll
    for (int j = 0; j < 4; j++) acc[c4][j] = 0.f;

  const int arow = wid * 16 + m15;
#pragma unroll
  for (int c = 0; c < 2; c++) {
    const int ua = arow * 8 + ((c * 4 + quad) ^ (arow & 7));
    const short8 aA = __builtin_bit_cast(short8, sAgg[ua]);
    const short8 aH = __builtin_bit_cast(short8, sH[ua]);
#pragma unroll
    for (int c4 = 0; c4 < 4; c4++) {
      const int col = c4 * 16 + m15;
      const int ub = col * 8 + ((c * 4 + quad) ^ (col & 7));
      acc[c4] = __builtin_amdgcn_mfma_f32_16x16x32_bf16(
          aA, __builtin_bit_cast(short8, sWl[ub]), acc[c4], 0, 0, 0);
      acc[c4] = __builtin_amdgcn_mfma_f32_16x16x32_bf16(
          aH, __builtin_bit_cast(short8, sWr[ub]), acc[c4], 0, 0, 0);
    }
  }

  // ---- epilogue: residual + bias + relu; bf16(+fp8) store; optional cls ----
  float vals[4][4];
#pragma unroll
  for (int c4 = 0; c4 < 4; c4++) {
    const float bias = bl[c4 * 16 + m15];
#pragma unroll
    for (int r = 0; r < 4; r++) {
      const int rowl = wid * 16 + quad * 4 + r;
      const unsigned short hv =
          ((const unsigned short*)
               sH)[(rowl * 8 + ((c4 * 2 + (m15 >> 3)) ^ (rowl & 7))) * 8 +
                   (m15 & 7)];
      const float v = __uint_as_float((unsigned)hv << 16) + acc[c4][r] + bias;
      vals[c4][r] = v > 0.f ? v : 0.f;
    }
  }
#pragma unroll
  for (int c4 = 0; c4 < 4; c4++) {
#pragma unroll
    for (int r = 0; r < 4; r++) {
      const int rowg = blockBase + wid * 16 + quad * 4 + r;
      if (rowg < N)
        hout[(size_t)rowg * HID + c4 * 16 + m15] = bf16one(vals[c4][r]);
    }
  }
  if (h8out != nullptr) {
#pragma unroll
    for (int c4 = 0; c4 < 4; c4++) {
#pragma unroll
      for (int r = 0; r < 4; r++) {
        const int rowg = blockBase + wid * 16 + quad * 4 + r;
        if (rowg < N)
          h8out[(size_t)rowg * HID + c4 * 16 + m15] = fp8q(vals[c4][r]);
      }
    }
  }
  if (Wc != nullptr) {
    float p[4] = {0.f, 0.f, 0.f, 0.f};
#pragma unroll
    for (int c4 = 0; c4 < 4; c4++) {
      const float wc = Wc[c4 * 16 + m15];
#pragma unroll
      for (int r = 0; r < 4; r++) p[r] += vals[c4][r] * wc;
    }
#pragma unroll
    for (int off = 1; off < 16; off <<= 1) {
#pragma unroll
      for (int r = 0; r < 4; r++) p[r] += __shfl_xor(p[r], off, 16);
    }
    if (m15 == 0) {
      const float bb = bc[0];
#pragma unroll
      for (int r = 0; r < 4; r++) {
        const int rowg = blockBase + wid * 16 + quad * 4 + r;
        if (rowg < N) out[rowg] = 1.0f / (1.0f + expf(-(p[r] + bb)));
      }
    }
  }
}

extern "C" void kernel_launch(void* const* d_in, const int* in_sizes, int n_in,
                              void* d_out, int out_size, void* d_ws,
                              size_t ws_size, hipStream_t stream) {
  const float* x = (const float*)d_in[0];
  const int* ei = (const int*)d_in[1];
  const float* W_enc = (const float*)d_in[2];
  const float* b_enc = (const float*)d_in[3];
  const float* Wl = (const float*)d_in[4];
  const float* bl = (const float*)d_in[5];
  const float* Wr = (const float*)d_in[6];
  const float* Wc = (const float*)d_in[7];
  const float* bc = (const float*)d_in[8];
  float* out = (float*)d_out;

  const int N = in_sizes[0] / KIN;
  const int E = in_sizes[1] / 2;
  const int* src = ei;
  const int* dst = ei + E;

  char* ws = (char*)d_ws;
  size_t off = 0;
  auto alloc = [&](size_t bytes) -> void* {
    void* p = ws + off;
    off += (bytes + 255) & ~(size_t)255;
    return p;
  };
  unsigned short* hb0 =
      (unsigned short*)alloc((size_t)N * HID * sizeof(unsigned short));
  unsigned short* hb1 =
      (unsigned short*)alloc((size_t)N * HID * sizeof(unsigned short));
  unsigned char* h8a = (unsigned char*)alloc((size_t)N * HID);
  unsigned char* h8b = (unsigned char*)alloc((size_t)N * HID);
  // zero-init region: cnt, cursor (single memset)
  char* zbase = ws + off;
  int* cnt = (int*)alloc((size_t)N * sizeof(int));
  int* cursor = (int*)alloc((size_t)N * sizeof(int));
  const size_t zbytes = (ws + off) - zbase;
  int* row_start = (int*)alloc((size_t)(N + 1) * sizeof(int));
  float* inv_deg = (float*)alloc((size_t)N * sizeof(float));
  int* csr_src = (int*)alloc((size_t)E * sizeof(int));
  const int nblk = (N + 1023) / 1024;
  int* block_sums = (int*)alloc((size_t)nblk * sizeof(int));
  unsigned short* wte =
      (unsigned short*)alloc((size_t)HID * KIN * sizeof(unsigned short));
  unsigned short* wlrt =
      (unsigned short*)alloc((size_t)6 * HID * HID * sizeof(unsigned short));

  hipMemsetAsync(zbase, 0, zbytes, stream);

  prep_kernel<<<224, 256, 0, stream>>>(W_enc, Wl, Wr, wte, wlrt);
  hist_kernel<<<(E + 255) / 256, 256, 0, stream>>>(dst, cnt, E, N);
  scanA_kernel<<<nblk, 1024, 0, stream>>>(cnt, block_sums, N);
  scanB_kernel<<<1, 128, 0, stream>>>(block_sums, row_start, nblk, N);
  scanC_kernel<<<nblk, 1024, 0, stream>>>(cnt, block_sums, row_start, inv_deg,
                                          N);
  scatter_kernel<<<(E + 255) / 256, 256, 0, stream>>>(src, dst, row_start,
                                                      cursor, csr_src, E, N);
  enc_kernel<<<(N + 63) / 64, 256, 0, stream>>>(x, wte, b_enc, hb0, h8a, N);

  const int nb64 = (N + 63) / 64;
  // layer 0: hb0/h8a -> hb1/h8b
  layer_kernel<<<nb64, 256, 0, stream>>>(hb0, h8a, hb1, h8b, row_start, csr_src,
                                         inv_deg, wlrt, wlrt + 3 * 4096, bl,
                                         nullptr, nullptr, nullptr, N);
  // layer 1: hb1/h8b -> hb0/h8a
  layer_kernel<<<nb64, 256, 0, stream>>>(hb1, h8b, hb0, h8a, row_start, csr_src,
                                         inv_deg, wlrt + 4096, wlrt + 4 * 4096,
                                         bl + 64, nullptr, nullptr, nullptr, N);
  // layer 2: hb0/h8a -> hb1 (no fp8 out), fused classifier
  layer_kernel<<<nb64, 256, 0, stream>>>(hb0, h8a, hb1, nullptr, row_start,
                                         csr_src, inv_deg, wlrt + 2 * 4096,
                                         wlrt + 5 * 4096, bl + 128, Wc, bc, out,
                                         N);
}

// Round 11
// 515.097 us; speedup vs baseline: 1.6601x; 1.0907x over previous
//
#include <hip/hip_runtime.h>
#include <math.h>

#define HID 64
#define KIN 512

typedef __attribute__((ext_vector_type(8))) short short8;   // 8 bf16 (4 VGPR)
typedef __attribute__((ext_vector_type(4))) float floatx4;  // MFMA acc

// RNE fp32 -> bf16
__device__ inline unsigned bf16pair(float a, float b) {
  unsigned ua = __float_as_uint(a);
  unsigned ub = __float_as_uint(b);
  ua = (ua + 0x7FFFu + ((ua >> 16) & 1u)) >> 16;
  ub = (ub + 0x7FFFu + ((ub >> 16) & 1u)) >> 16;
  return ua | (ub << 16);
}
__device__ inline unsigned short bf16one(float a) {
  unsigned ua = __float_as_uint(a);
  return (unsigned short)((ua + 0x7FFFu + ((ua >> 16) & 1u)) >> 16);
}
// fp8 e4m3 (OCP) quantize one float -> byte, via HW pack cvt
__device__ inline unsigned char fp8q(float a) {
  const int pk = __builtin_amdgcn_cvt_pk_fp8_f32(a, a, 0, false);
  return (unsigned char)(pk & 0xff);
}

// ==== K1: weight prep (blocks 0..223) + degree hist w/ rank (blocks 224..) ====
__global__ __launch_bounds__(256) void prep_hist_kernel(
    const float* __restrict__ We, const float* __restrict__ Wl,
    const float* __restrict__ Wr, unsigned short* __restrict__ wte,
    unsigned short* __restrict__ wlrt, const int* __restrict__ dst,
    int* __restrict__ cnt, int* __restrict__ rank, int E, int N) {
  const int blk = blockIdx.x;
  const int tid = threadIdx.x;
  if (blk < 128) {
    const int t = blk * 256 + tid;
    const int c = t >> 9, k = t & 511;
    wte[c * KIN + k] = bf16one(We[k * HID + c]);
  } else if (blk < 224) {
    const int t = (blk - 128) * 256 + tid;  // 0..24575
    const int mat = t >> 12;                // 0..5
    const int e = t & 4095;
    const int c = e >> 6, k = e & 63;
    const float* src =
        (mat < 3) ? (Wl + (size_t)mat * 4096) : (Wr + (size_t)(mat - 3) * 4096);
    wlrt[(size_t)mat * 4096 + c * 64 + k] = bf16one(src[k * 64 + c]);
  } else {
    const int e = (blk - 224) * 256 + tid;
    if (e < E) {
      const int d = dst[e];
      if ((unsigned)d < (unsigned)N) rank[e] = atomicAdd(&cnt[d], 1);
    }
  }
}

// ==== K2: block sums over cnt ====
__global__ __launch_bounds__(1024) void scanA_kernel(
    const int* __restrict__ cnt, int* __restrict__ block_sums, int N) {
  __shared__ int red[1024];
  const int tid = threadIdx.x;
  const int i = blockIdx.x * 1024 + tid;
  red[tid] = (i < N) ? cnt[i] : 0;
  __syncthreads();
  for (int off = 512; off > 0; off >>= 1) {
    if (tid < off) red[tid] += red[tid + off];
    __syncthreads();
  }
  if (tid == 0) block_sums[blockIdx.x] = red[0];
}

// ==== K3: local scan + inline prefix of preceding block sums ====
// (replaces scanB+scanC: each block sums its <=nblk-1 predecessors itself)
__global__ __launch_bounds__(1024) void scanC_kernel(
    const int* __restrict__ cnt, const int* __restrict__ block_sums,
    int* __restrict__ row_start, float* __restrict__ inv_deg, int N) {
  __shared__ int part[1024];
  __shared__ int soff;
  const int tid = threadIdx.x;
  const int i = blockIdx.x * 1024 + tid;
  if (tid < 64) {  // wave 0: prefix of preceding block sums
    int s = 0;
    for (int b2 = tid; b2 < blockIdx.x; b2 += 64) s += block_sums[b2];
#pragma unroll
    for (int off = 32; off > 0; off >>= 1) s += __shfl_down(s, off, 64);
    if (tid == 0) soff = s;
  }
  const int v = (i < N) ? cnt[i] : 0;
  part[tid] = v;
  __syncthreads();
  for (int off = 1; off < 1024; off <<= 1) {
    int t = (tid >= off) ? part[tid - off] : 0;
    __syncthreads();
    part[tid] += t;
    __syncthreads();
  }
  if (i < N) {
    row_start[i] = soff + part[tid] - v;
    inv_deg[i] = (v > 0) ? 1.0f / (float)v : 0.0f;
  }
  if (blockIdx.x == gridDim.x - 1 && tid == 1023)
    row_start[N] = soff + part[1023];
}

// ==== K4: CSR scatter (atomic-free, rank-based) + encoder, fused ====
// blocks [0, nscat): csr_src[row_start[d]+rank[e]] = src[e]
// blocks [nscat, ...): hb = bf16(x @ W_enc + b_enc), h8 = fp8 copy
__global__ __launch_bounds__(256) void scatter_enc_kernel(
    const int* __restrict__ src, const int* __restrict__ dst,
    const int* __restrict__ row_start, const int* __restrict__ rank,
    int* __restrict__ csr_src, const float* __restrict__ x,
    const unsigned short* __restrict__ wt, const float* __restrict__ b,
    unsigned short* __restrict__ hb, unsigned char* __restrict__ h8, int E,
    int N) {
  __shared__ uint4 sx[2][256];
  __shared__ uint4 sw[2][256];
  const int nscat = (E + 255) >> 8;
  if (blockIdx.x < nscat) {
    const int e = blockIdx.x * 256 + threadIdx.x;
    if (e < E) {
      const int d = dst[e];
      if ((unsigned)d < (unsigned)N) {
        int s = src[e];
        if ((unsigned)s >= (unsigned)N) s = 0;
        csr_src[row_start[d] + rank[e]] = s;
      }
    }
    return;
  }
  // ---- encoder ----
  const int t = threadIdx.x;
  const int lane = t & 63;
  const int wid = t >> 6;
  const int m15 = lane & 15;
  const int quad = lane >> 4;
  const int blockBase = (blockIdx.x - nscat) * 64;

  const int rs = t >> 2;
  const int qs = t & 3;
  const int us = rs * 4 + (qs ^ ((rs >> 1) & 3));
  const int gn = blockBase + rs;
  const bool valid = gn < N;
  const float* xp = x + (size_t)(valid ? gn : 0) * KIN + qs * 8;
  const unsigned short* wp = wt + (size_t)rs * KIN + qs * 8;

  const int arow = wid * 16 + m15;
  const int ua = arow * 4 + (quad ^ ((arow >> 1) & 3));
  int ub[4];
#pragma unroll
  for (int c4 = 0; c4 < 4; c4++) {
    const int col = c4 * 16 + m15;
    ub[c4] = col * 4 + (quad ^ ((col >> 1) & 3));
  }

  floatx4 acc[4];
#pragma unroll
  for (int c4 = 0; c4 < 4; c4++)
#pragma unroll
    for (int j = 0; j < 4; j++) acc[c4][j] = 0.f;

  float4 fx0, fx1;
  uint4 wv;
  if (valid) {
    fx0 = *(const float4*)(xp);
    fx1 = *(const float4*)(xp + 4);
  } else {
    fx0 = fx1 = make_float4(0.f, 0.f, 0.f, 0.f);
  }
  wv = *(const uint4*)(wp);

  for (int kc = 0; kc < 16; kc++) {
    const int cur = kc & 1;
    uint4 xu;
    xu.x = bf16pair(fx0.x, fx0.y);
    xu.y = bf16pair(fx0.z, fx0.w);
    xu.z = bf16pair(fx1.x, fx1.y);
    xu.w = bf16pair(fx1.z, fx1.w);
    sx[cur][us] = xu;
    sw[cur][us] = wv;
    __syncthreads();
    if (kc < 15) {
      const int ko = (kc + 1) * 32;
      if (valid) {
        fx0 = *(const float4*)(xp + ko);
        fx1 = *(const float4*)(xp + ko + 4);
      }
      wv = *(const uint4*)(wp + ko);
    }
    const short8 a = __builtin_bit_cast(short8, sx[cur][ua]);
#pragma unroll
    for (int c4 = 0; c4 < 4; c4++) {
      const short8 bf = __builtin_bit_cast(short8, sw[cur][ub[c4]]);
      acc[c4] =
          __builtin_amdgcn_mfma_f32_16x16x32_bf16(a, bf, acc[c4], 0, 0, 0);
    }
  }

#pragma unroll
  for (int c4 = 0; c4 < 4; c4++) {
    const float bias = b[c4 * 16 + m15];
#pragma unroll
    for (int r = 0; r < 4; r++) {
      const int row = blockBase + wid * 16 + quad * 4 + r;
      if (row < N) {
        const float v = acc[c4][r] + bias;
        hb[(size_t)row * HID + c4 * 16 + m15] = bf16one(v);
        h8[(size_t)row * HID + c4 * 16 + m15] = fp8q(v);
      }
    }
  }
}

// ===== fused layer: fp8 gather-mean -> [agg|h]@[Wl;Wr] MFMA -> residual/relu
//       -> bf16(+fp8) store (+ optional classifier on last layer) =====
__global__ __launch_bounds__(256) void layer_kernel(
    const unsigned short* __restrict__ hin,
    const unsigned char* __restrict__ h8in, unsigned short* __restrict__ hout,
    unsigned char* __restrict__ h8out, const int* __restrict__ row_start,
    const int* __restrict__ csr_src, const float* __restrict__ inv_deg,
    const unsigned short* __restrict__ Wlt,
    const unsigned short* __restrict__ Wrt, const float* __restrict__ bl,
    const float* __restrict__ Wc, const float* __restrict__ bc,
    float* __restrict__ out, int N) {
  __shared__ uint4 sAgg[512];  // 8 KB agg tile (bf16)
  __shared__ uint4 sH[512];    // 8 KB own h rows (bf16)
  __shared__ uint4 sWl[512];   // 8 KB Wl^T bf16
  __shared__ uint4 sWr[512];   // 8 KB Wr^T bf16
  const int tid = threadIdx.x;
  const int lane = tid & 63;
  const int wid = tid >> 6;
  const int m15 = lane & 15;
  const int quad = lane >> 4;
  const int blockBase = blockIdx.x * 64;

  // ---- stage own h rows + both weight mats ----
  {
    const int r = tid >> 2;
    const int gp = tid & 3;
    const int g0 = gp * 2, g1 = gp * 2 + 1;
    const int u0 = r * 8 + (g0 ^ (r & 7));
    const int u1 = r * 8 + (g1 ^ (r & 7));
    const int gn = blockBase + r;
    if (gn < N) {
      const uint4* hp = (const uint4*)(hin + (size_t)gn * HID);
      sH[u0] = hp[g0];
      sH[u1] = hp[g1];
    } else {
      const uint4 z = make_uint4(0, 0, 0, 0);
      sH[u0] = z;
      sH[u1] = z;
    }
    const uint4* wl = (const uint4*)(Wlt + (size_t)r * HID);
    const uint4* wr = (const uint4*)(Wrt + (size_t)r * HID);
    sWl[u0] = wl[g0];
    sWl[u1] = wl[g1];
    sWr[u0] = wr[g0];
    sWr[u1] = wr[g1];
  }

  // ---- mean-aggregate neighbors (fp8 rows) into sAgg ----
  {
    const int slot = lane >> 2;  // 0..15: node slot
    const int qc = lane & 3;     // 0..3: 16B group (16 fp8 cols)
    const int nl = wid * 16 + slot;
    const int gn = blockBase + nl;
    float a[16];
#pragma unroll
    for (int c = 0; c < 16; c++) a[c] = 0.f;
    float id = 0.f;
    if (gn < N) {
      id = inv_deg[gn];
      const int s = row_start[gn];
      const int e = row_start[gn + 1];
      for (int j = s; j < e; j += 8) {
        int n[8];
        bool ok[8];
#pragma unroll
        for (int u = 0; u < 8; u++) {
          const int jj = j + u;
          ok[u] = jj < e;
          n[u] = csr_src[ok[u] ? jj : j];
        }
        uint4 v[8];
#pragma unroll
        for (int u = 0; u < 8; u++) {
          v[u] = *(const uint4*)(h8in + (size_t)n[u] * HID + qc * 16);
        }
#pragma unroll
        for (int u = 0; u < 8; u++) {
          if (!ok[u]) v[u] = make_uint4(0, 0, 0, 0);
          a[0] += __builtin_amdgcn_cvt_f32_fp8(v[u].x, 0);
          a[1] += __builtin_amdgcn_cvt_f32_fp8(v[u].x, 1);
          a[2] += __builtin_amdgcn_cvt_f32_fp8(v[u].x, 2);
          a[3] += __builtin_amdgcn_cvt_f32_fp8(v[u].x, 3);
          a[4] += __builtin_amdgcn_cvt_f32_fp8(v[u].y, 0);
          a[5] += __builtin_amdgcn_cvt_f32_fp8(v[u].y, 1);
          a[6] += __builtin_amdgcn_cvt_f32_fp8(v[u].y, 2);
          a[7] += __builtin_amdgcn_cvt_f32_fp8(v[u].y, 3);
          a[8] += __builtin_amdgcn_cvt_f32_fp8(v[u].z, 0);
          a[9] += __builtin_amdgcn_cvt_f32_fp8(v[u].z, 1);
          a[10] += __builtin_amdgcn_cvt_f32_fp8(v[u].z, 2);
          a[11] += __builtin_amdgcn_cvt_f32_fp8(v[u].z, 3);
          a[12] += __builtin_amdgcn_cvt_f32_fp8(v[u].w, 0);
          a[13] += __builtin_amdgcn_cvt_f32_fp8(v[u].w, 1);
          a[14] += __builtin_amdgcn_cvt_f32_fp8(v[u].w, 2);
          a[15] += __builtin_amdgcn_cvt_f32_fp8(v[u].w, 3);
        }
      }
    }
    uint4 p0, p1;
    p0.x = bf16pair(a[0] * id, a[1] * id);
    p0.y = bf16pair(a[2] * id, a[3] * id);
    p0.z = bf16pair(a[4] * id, a[5] * id);
    p0.w = bf16pair(a[6] * id, a[7] * id);
    p1.x = bf16pair(a[8] * id, a[9] * id);
    p1.y = bf16pair(a[10] * id, a[11] * id);
    p1.z = bf16pair(a[12] * id, a[13] * id);
    p1.w = bf16pair(a[14] * id, a[15] * id);
    sAgg[nl * 8 + ((qc * 2) ^ (nl & 7))] = p0;
    sAgg[nl * 8 + ((qc * 2 + 1) ^ (nl & 7))] = p1;
  }
  __syncthreads();

  // ---- MFMA: acc = agg@Wl + h@Wr ----
  floatx4 acc[4];
#pragma unroll
  for (int c4 = 0; c4 < 4; c4++)
#pragma unroll
    for (int j = 0; j < 4; j++) acc[c4][j] = 0.f;

  const int arow = wid * 16 + m15;
#pragma unroll
  for (int c = 0; c < 2; c++) {
    const int ua = arow * 8 + ((c * 4 + quad) ^ (arow & 7));
    const short8 aA = __builtin_bit_cast(short8, sAgg[ua]);
    const short8 aH = __builtin_bit_cast(short8, sH[ua]);
#pragma unroll
    for (int c4 = 0; c4 < 4; c4++) {
      const int col = c4 * 16 + m15;
      const int ub = col * 8 + ((c * 4 + quad) ^ (col & 7));
      acc[c4] = __builtin_amdgcn_mfma_f32_16x16x32_bf16(
          aA, __builtin_bit_cast(short8, sWl[ub]), acc[c4], 0, 0, 0);
      acc[c4] = __builtin_amdgcn_mfma_f32_16x16x32_bf16(
          aH, __builtin_bit_cast(short8, sWr[ub]), acc[c4], 0, 0, 0);
    }
  }

  // ---- epilogue: residual + bias + relu; bf16(+fp8) store; optional cls ----
  float vals[4][4];
#pragma unroll
  for (int c4 = 0; c4 < 4; c4++) {
    const float bias = bl[c4 * 16 + m15];
#pragma unroll
    for (int r = 0; r < 4; r++) {
      const int rowl = wid * 16 + quad * 4 + r;
      const unsigned short hv =
          ((const unsigned short*)
               sH)[(rowl * 8 + ((c4 * 2 + (m15 >> 3)) ^ (rowl & 7))) * 8 +
                   (m15 & 7)];
      const float v = __uint_as_float((unsigned)hv << 16) + acc[c4][r] + bias;
      vals[c4][r] = v > 0.f ? v : 0.f;
    }
  }
#pragma unroll
  for (int c4 = 0; c4 < 4; c4++) {
#pragma unroll
    for (int r = 0; r < 4; r++) {
      const int rowg = blockBase + wid * 16 + quad * 4 + r;
      if (rowg < N)
        hout[(size_t)rowg * HID + c4 * 16 + m15] = bf16one(vals[c4][r]);
    }
  }
  if (h8out != nullptr) {
#pragma unroll
    for (int c4 = 0; c4 < 4; c4++) {
#pragma unroll
      for (int r = 0; r < 4; r++) {
        const int rowg = blockBase + wid * 16 + quad * 4 + r;
        if (rowg < N)
          h8out[(size_t)rowg * HID + c4 * 16 + m15] = fp8q(vals[c4][r]);
      }
    }
  }
  if (Wc != nullptr) {
    float p[4] = {0.f, 0.f, 0.f, 0.f};
#pragma unroll
    for (int c4 = 0; c4 < 4; c4++) {
      const float wc = Wc[c4 * 16 + m15];
#pragma unroll
      for (int r = 0; r < 4; r++) p[r] += vals[c4][r] * wc;
    }
#pragma unroll
    for (int off = 1; off < 16; off <<= 1) {
#pragma unroll
      for (int r = 0; r < 4; r++) p[r] += __shfl_xor(p[r], off, 16);
    }
    if (m15 == 0) {
      const float bb = bc[0];
#pragma unroll
      for (int r = 0; r < 4; r++) {
        const int rowg = blockBase + wid * 16 + quad * 4 + r;
        if (rowg < N) out[rowg] = 1.0f / (1.0f + expf(-(p[r] + bb)));
      }
    }
  }
}

extern "C" void kernel_launch(void* const* d_in, const int* in_sizes, int n_in,
                              void* d_out, int out_size, void* d_ws,
                              size_t ws_size, hipStream_t stream) {
  const float* x = (const float*)d_in[0];
  const int* ei = (const int*)d_in[1];
  const float* W_enc = (const float*)d_in[2];
  const float* b_enc = (const float*)d_in[3];
  const float* Wl = (const float*)d_in[4];
  const float* bl = (const float*)d_in[5];
  const float* Wr = (const float*)d_in[6];
  const float* Wc = (const float*)d_in[7];
  const float* bc = (const float*)d_in[8];
  float* out = (float*)d_out;

  const int N = in_sizes[0] / KIN;
  const int E = in_sizes[1] / 2;
  const int* src = ei;
  const int* dst = ei + E;

  char* ws = (char*)d_ws;
  size_t off = 0;
  auto alloc = [&](size_t bytes) -> void* {
    void* p = ws + off;
    off += (bytes + 255) & ~(size_t)255;
    return p;
  };
  unsigned short* hb0 =
      (unsigned short*)alloc((size_t)N * HID * sizeof(unsigned short));
  unsigned short* hb1 =
      (unsigned short*)alloc((size_t)N * HID * sizeof(unsigned short));
  unsigned char* h8a = (unsigned char*)alloc((size_t)N * HID);
  unsigned char* h8b = (unsigned char*)alloc((size_t)N * HID);
  int* cnt = (int*)alloc((size_t)N * sizeof(int));  // zeroed below
  int* rank = (int*)alloc((size_t)E * sizeof(int));
  int* row_start = (int*)alloc((size_t)(N + 1) * sizeof(int));
  float* inv_deg = (float*)alloc((size_t)N * sizeof(float));
  int* csr_src = (int*)alloc((size_t)E * sizeof(int));
  const int nblk = (N + 1023) / 1024;
  int* block_sums = (int*)alloc((size_t)nblk * sizeof(int));
  unsigned short* wte =
      (unsigned short*)alloc((size_t)HID * KIN * sizeof(unsigned short));
  unsigned short* wlrt =
      (unsigned short*)alloc((size_t)6 * HID * HID * sizeof(unsigned short));

  hipMemsetAsync(cnt, 0, (size_t)N * sizeof(int), stream);

  const int nhist = (E + 255) / 256;
  prep_hist_kernel<<<224 + nhist, 256, 0, stream>>>(W_enc, Wl, Wr, wte, wlrt,
                                                    dst, cnt, rank, E, N);
  scanA_kernel<<<nblk, 1024, 0, stream>>>(cnt, block_sums, N);
  scanC_kernel<<<nblk, 1024, 0, stream>>>(cnt, block_sums, row_start, inv_deg,
                                          N);
  const int nscat = (E + 255) / 256;
  const int nb64 = (N + 63) / 64;
  scatter_enc_kernel<<<nscat + nb64, 256, 0, stream>>>(
      src, dst, row_start, rank, csr_src, x, wte, b_enc, hb0, h8a, E, N);

  // layer 0: hb0/h8a -> hb1/h8b
  layer_kernel<<<nb64, 256, 0, stream>>>(hb0, h8a, hb1, h8b, row_start, csr_src,
                                         inv_deg, wlrt, wlrt + 3 * 4096, bl,
                                         nullptr, nullptr, nullptr, N);
  // layer 1: hb1/h8b -> hb0/h8a
  layer_kernel<<<nb64, 256, 0, stream>>>(hb1, h8b, hb0, h8a, row_start, csr_src,
                                         inv_deg, wlrt + 4096, wlrt + 4 * 4096,
                                         bl + 64, nullptr, nullptr, nullptr, N);
  // layer 2: hb0/h8a -> hb1 (no fp8 out), fused classifier
  layer_kernel<<<nb64, 256, 0, stream>>>(hb0, h8a, hb1, nullptr, row_start,
                                         csr_src, inv_deg, wlrt + 2 * 4096,
                                         wlrt + 5 * 4096, bl + 128, Wc, bc, out,
                                         N);
}